// Round 8
// baseline (359.835 us; speedup 1.0000x reference)
//
#include <hip/hip_runtime.h>
#include <math.h>

#define D_MODEL 1024
#define NHEAD   16
#define DKH     64
#define DFF_    4096
#define BB      2
#define SS      2048
#define MTOT    (BB*SS)
#define EPSLN   1e-6f
#define NEG_SLOPE 0.01f

typedef unsigned short u16;
typedef unsigned int   u32;
typedef __bf16 bf16x8 __attribute__((ext_vector_type(8)));
typedef float  f32x4  __attribute__((ext_vector_type(4)));
typedef u16    u16x4  __attribute__((ext_vector_type(4)));

__device__ __forceinline__ u16 f2bf(float f) {
    u32 u = __float_as_uint(f);
    u = (u + 0x7fffu + ((u >> 16) & 1u)) >> 16;
    return (u16)u;
}
__device__ __forceinline__ float bf2f(u16 u) {
    return __uint_as_float(((u32)u) << 16);
}

__device__ __forceinline__ void gload_lds16(const u16* g, u16* l) {
    __builtin_amdgcn_global_load_lds(
        (const __attribute__((address_space(1))) u32*)g,
        (__attribute__((address_space(3))) u32*)l,
        16, 0, 0);
}

// ---------------------------------------------------------------------------
// 64x64 fp32->bf16 transpose tile (device helper for prep kernel)
// ---------------------------------------------------------------------------
__device__ __forceinline__ void transpose_tile(const float* __restrict__ W,
        u16* __restrict__ WT, int N, int out_stride, int out_row_off,
        float scale, int bx, int by, u16* T)
{
    const int t  = threadIdx.x;
    const int n0 = bx * 64;
    const int k0 = by * 64;
    #pragma unroll
    for (int i = 0; i < 4; ++i) {
        int r = i * 16 + (t >> 4);          // k
        int c = (t & 15) * 4;               // n
        float4 v = *(const float4*)&W[(size_t)(k0 + r) * N + n0 + c];
        T[(c + 0) * 72 + r] = f2bf(v.x * scale);
        T[(c + 1) * 72 + r] = f2bf(v.y * scale);
        T[(c + 2) * 72 + r] = f2bf(v.z * scale);
        T[(c + 3) * 72 + r] = f2bf(v.w * scale);
    }
    __syncthreads();
    #pragma unroll
    for (int i = 0; i < 4; ++i) {
        int nr = i * 16 + (t >> 4);
        int kc = (t & 15) * 4;
        u16x4 o = { T[nr*72 + kc], T[nr*72 + kc + 1], T[nr*72 + kc + 2], T[nr*72 + kc + 3] };
        *(u16x4*)&WT[(size_t)(out_row_off + n0 + nr) * out_stride + k0 + kc] = o;
    }
}

// ---------------------------------------------------------------------------
// Fused prep: x f32->bf16 | 4 square W transposes | ff1 | ff2 | bias concat.
// ---------------------------------------------------------------------------
__global__ __launch_bounds__(256)
void prep(const float* __restrict__ x, u16* __restrict__ x_bf,
          const float* __restrict__ wq, const float* __restrict__ wk,
          const float* __restrict__ wv, const float* __restrict__ wo,
          const float* __restrict__ wff1, const float* __restrict__ wff2,
          u16* __restrict__ wqkvT, u16* __restrict__ woT,
          u16* __restrict__ wff1T, u16* __restrict__ wff2T,
          const float* __restrict__ bq, const float* __restrict__ bk,
          const float* __restrict__ bv, float* __restrict__ qkv_bias,
          float qscale)
{
    __shared__ u16 T[64 * 72];
    int blk = blockIdx.x;
    if (blk < 4096) {
        int i = blk * 256 + threadIdx.x;
        float4 v = ((const float4*)x)[i];
        u16x4 o = { f2bf(v.x), f2bf(v.y), f2bf(v.z), f2bf(v.w) };
        ((u16x4*)x_bf)[i] = o;
        return;
    }
    blk -= 4096;
    if (blk < 1024) {   // wq/wk/wv/wo
        int which = blk >> 8, r = blk & 255;
        const float* Ws = which == 0 ? wq : which == 1 ? wk : which == 2 ? wv : wo;
        u16* Wd   = which == 3 ? woT : wqkvT;
        int off   = which == 3 ? 0 : which * 1024;
        float sc  = which == 0 ? qscale : 1.0f;
        transpose_tile(Ws, Wd, 1024, 1024, off, sc, r & 15, r >> 4, T);
        return;
    }
    blk -= 1024;
    if (blk < 1024) {
        transpose_tile(wff1, wff1T, 4096, 1024, 0, 1.0f, blk & 63, blk >> 6, T);
        return;
    }
    blk -= 1024;
    if (blk < 1024) {
        transpose_tile(wff2, wff2T, 1024, 4096, 0, 1.0f, blk & 15, blk >> 4, T);
        return;
    }
    blk -= 1024;
    int i = blk * 256 + threadIdx.x;
    qkv_bias[i] = (i < 1024) ? bq[i] * qscale
                : (i < 2048) ? bk[i - 1024] : bv[i - 2048];
}

// ---------------------------------------------------------------------------
// bf16 MFMA GEMM: C[M,N] = A[M, k_off:+k_len] @ BT[N,...]^T (+ bias).
// 128x128 tile, BK=64 (32 MFMA per barrier pair), global_load_lds staging
// with XOR chunk swizzle.
// EPI: 1 = bf16 + bias + LeakyReLU
//      3 = bf16 partials (no bias) at Cout + z*M*N
//      4 = QKV special: cols <2048 bf16+bias into QKV; cols >=2048 (V)
//          written transposed into Vt[bh*64+d][SS]
// ---------------------------------------------------------------------------
template<int EPI>
__global__ __launch_bounds__(256)
void gemm_bf16(const u16* __restrict__ A, const u16* __restrict__ BT,
               const float* __restrict__ bias, void* __restrict__ Cout,
               u16* __restrict__ Vt, int M, int N, int k_len, int kstride)
{
    __shared__ u16 As[128 * 64];
    __shared__ u16 Bs[128 * 64];
    const int tid  = threadIdx.x;
    const int w    = tid >> 6;
    const int lane = tid & 63;
    const int lm   = lane & 15;
    const int lq   = lane >> 4;
    const int row0 = blockIdx.y * 128;
    const int col0 = blockIdx.x * 128;
    const int k_off = blockIdx.z * k_len;
    const int wrow = (w >> 1) * 64;
    const int wcol = (w & 1) * 64;

    f32x4 acc[4][4] = {};

    const int r_i = lane >> 3;                 // 0..7 row in 8-group
    const int csw = ((lane & 7) ^ r_i) * 8;    // swizzled src chunk offset
    const u16* a_src = A  + (size_t)(row0 + w * 32 + r_i) * kstride + k_off + csw;
    const u16* b_src = BT + (size_t)(col0 + w * 32 + r_i) * kstride + k_off + csw;
    u16* a_dst = &As[(w * 32) * 64];
    u16* b_dst = &Bs[(w * 32) * 64];

    const int fr0 = (lq ^ (lm & 7)) * 8;
    const int fr1 = ((4 + lq) ^ (lm & 7)) * 8;
    const u16* a_rd = &As[(wrow + lm) * 64];
    const u16* b_rd = &Bs[(wcol + lm) * 64];

    for (int k0 = 0; k0 < k_len; k0 += 64) {
        #pragma unroll
        for (int i = 0; i < 4; ++i) {
            gload_lds16(a_src + k0 + (size_t)(i * 8) * kstride, a_dst + (i * 8) * 64);
            gload_lds16(b_src + k0 + (size_t)(i * 8) * kstride, b_dst + (i * 8) * 64);
        }
        __syncthreads();
        #pragma unroll
        for (int h = 0; h < 2; ++h) {
            const int fo = h ? fr1 : fr0;
            bf16x8 av[4], bv[4];
            #pragma unroll
            for (int m = 0; m < 4; ++m) av[m] = *(const bf16x8*)(a_rd + m * 16 * 64 + fo);
            #pragma unroll
            for (int n = 0; n < 4; ++n) bv[n] = *(const bf16x8*)(b_rd + n * 16 * 64 + fo);
            #pragma unroll
            for (int m = 0; m < 4; ++m)
                #pragma unroll
                for (int n = 0; n < 4; ++n)
                    acc[m][n] = __builtin_amdgcn_mfma_f32_16x16x32_bf16(av[m], bv[n], acc[m][n], 0, 0, 0);
        }
        __syncthreads();
    }

    float bz[4] = {0.f, 0.f, 0.f, 0.f};
    if (EPI != 3) {
        #pragma unroll
        for (int n = 0; n < 4; ++n) bz[n] = bias[col0 + wcol + n * 16 + lm];
    }

    if (EPI == 4 && col0 >= 2048) {
        // V part -> Vt[(b*16+h)*64 + d][2048]
        #pragma unroll
        for (int m = 0; m < 4; ++m) {
            int rbase = row0 + wrow + m * 16 + lq * 4;
            int b = rbase >> 11, s = rbase & 2047;
            #pragma unroll
            for (int n = 0; n < 4; ++n) {
                int c = col0 + wcol + n * 16 + lm - 2048;
                u16x4 pk = { f2bf(acc[m][n][0] + bz[n]), f2bf(acc[m][n][1] + bz[n]),
                             f2bf(acc[m][n][2] + bz[n]), f2bf(acc[m][n][3] + bz[n]) };
                *(u16x4*)&Vt[(size_t)((b * 16 + (c >> 6)) * 64 + (c & 63)) * 2048 + s] = pk;
            }
        }
        return;
    }

    u16* Cz = (u16*)Cout + (EPI == 3 ? (size_t)blockIdx.z * M * N : 0);
    #pragma unroll
    for (int m = 0; m < 4; ++m) {
        #pragma unroll
        for (int e = 0; e < 4; ++e) {
            int row = row0 + wrow + m * 16 + lq * 4 + e;
            #pragma unroll
            for (int n = 0; n < 4; ++n) {
                int col = col0 + wcol + n * 16 + lm;
                float v = acc[m][n][e] + bz[n];
                if (EPI == 1) v = v > 0.f ? v : NEG_SLOPE * v;
                Cz[(size_t)row * N + col] = f2bf(v);
            }
        }
    }
}

// ---------------------------------------------------------------------------
// Flash attention, bf16 MFMA. 128-query tile, 4 waves, 2 q-slabs per wave:
// each K/V fragment read from LDS feeds 2x MFMA (LDS-BW was the binding
// pipe at 1 slab). K/V staged via global_load_lds (XOR chunk swizzle) into
// double-buffered LDS, next-tile DMA issued at top of iter -> one barrier
// per key-tile. Q/P rows are wave-private -> no barrier on the P round-trip.
// No-max exp2 softmax (scale folded into Q weights); row sums via ones-MFMA.
// LDS = 16K QP + 16K Kb + 16K Vb = 48K -> grid 512 = 2 blocks/CU resident.
// ---------------------------------------------------------------------------
__global__ __launch_bounds__(256)
void attn_mfma(const u16* __restrict__ QKV, const u16* __restrict__ Vt,
               u16* __restrict__ ctx)
{
    __shared__ u16 QP[128 * 64];      // Q staged (swizzled); later P (swizzled)
    __shared__ u16 Kb[2][64 * 64];
    __shared__ u16 Vb[2][64 * 64];
    const int tid = threadIdx.x, w = tid >> 6, lane = tid & 63;
    const int lm = lane & 15, lq = lane >> 4;
    const int q0 = blockIdx.x * 128;
    const int bh = blockIdx.y;
    const int b  = bh >> 4, h = bh & 15;
    const size_t row_b = (size_t)b * SS;
    const int ccol = h * DKH;

    // staging geometry
    const int r_i = lane >> 3;                 // 0..7
    const int csw = ((lane & 7) ^ r_i) * 8;    // swizzled chunk offset
    const u16* ksrc = QKV + (row_b + w * 16 + r_i) * 3072 + 1024 + ccol + csw;
    const u16* vsrc = Vt + ((size_t)bh * 64 + w * 16 + r_i) * SS + csw;
    const u16* qsrc = QKV + (row_b + q0 + w * 32 + r_i) * 3072 + ccol + csw;

    // wave w stages (and owns) Q rows w*32..+31
    #pragma unroll
    for (int i = 0; i < 4; ++i)
        gload_lds16(qsrc + (size_t)(i * 8) * 3072, &QP[(w * 32 + i * 8) * 64]);
    #pragma unroll
    for (int i = 0; i < 2; ++i) {
        gload_lds16(ksrc + (size_t)(i * 8) * 3072, &Kb[0][(w * 16 + i * 8) * 64]);
        gload_lds16(vsrc + (size_t)(i * 8) * SS,   &Vb[0][(w * 16 + i * 8) * 64]);
    }
    __syncthreads();   // drain DMA: Q/K0/V0 visible

    const int fr0 = (lq ^ (lm & 7)) * 8;
    const int fr1 = ((4 + lq) ^ (lm & 7)) * 8;
    bf16x8 aq00 = *(const bf16x8*)&QP[(w * 32 + lm) * 64 + fr0];
    bf16x8 aq01 = *(const bf16x8*)&QP[(w * 32 + lm) * 64 + fr1];
    bf16x8 aq10 = *(const bf16x8*)&QP[(w * 32 + 16 + lm) * 64 + fr0];
    bf16x8 aq11 = *(const bf16x8*)&QP[(w * 32 + 16 + lm) * 64 + fr1];
    __syncthreads();

    bf16x8 ones;
    #pragma unroll
    for (int j = 0; j < 8; ++j) ones[j] = (__bf16)1.0f;

    f32x4 o0[4] = {}, o1[4] = {};
    f32x4 lacc0 = {}, lacc1 = {};

    // P store addresses (loop-invariant): value (row, col) ->
    // QP[row*64 + ((col>>3)^(row&7))*8 + (col&7)], rows wave-private.
    const int rb = lq * 4;
    const int cw = lm & 7;

    for (int kt = 0; kt < SS / 64; ++kt) {
        const int cur = kt & 1;
        if (kt < SS / 64 - 1) {
            const int nxt = cur ^ 1;
            const size_t koff = (size_t)(kt + 1) * 64;
            #pragma unroll
            for (int i = 0; i < 2; ++i) {
                gload_lds16(ksrc + (koff + i * 8) * 3072, &Kb[nxt][(w * 16 + i * 8) * 64]);
                gload_lds16(vsrc + koff + (size_t)(i * 8) * SS, &Vb[nxt][(w * 16 + i * 8) * 64]);
            }
        }
        f32x4 s0[4] = {}, s1[4] = {};
        #pragma unroll
        for (int n = 0; n < 4; ++n) {
            bf16x8 bk0 = *(const bf16x8*)&Kb[cur][(n * 16 + lm) * 64 + fr0];
            bf16x8 bk1 = *(const bf16x8*)&Kb[cur][(n * 16 + lm) * 64 + fr1];
            s0[n] = __builtin_amdgcn_mfma_f32_16x16x32_bf16(aq00, bk0, s0[n], 0, 0, 0);
            s0[n] = __builtin_amdgcn_mfma_f32_16x16x32_bf16(aq01, bk1, s0[n], 0, 0, 0);
            s1[n] = __builtin_amdgcn_mfma_f32_16x16x32_bf16(aq10, bk0, s1[n], 0, 0, 0);
            s1[n] = __builtin_amdgcn_mfma_f32_16x16x32_bf16(aq11, bk1, s1[n], 0, 0, 0);
        }
        // P = 2^S, wave-private rows, stride-64 XOR-swizzled store
        #pragma unroll
        for (int n = 0; n < 4; ++n) {
            const int cb = n * 2 + (lm >> 3);
            #pragma unroll
            for (int e = 0; e < 4; ++e) {
                const int sw = ((cb ^ ((rb + e) & 7)) * 8) + cw;
                float p0 = __builtin_exp2f(s0[n][e]);
                float p1 = __builtin_exp2f(s1[n][e]);
                QP[(w * 32 + rb + e) * 64 + sw] =
                    (u16)((__float_as_uint(p0) + 0x8000u) >> 16);
                QP[(w * 32 + 16 + rb + e) * 64 + sw] =
                    (u16)((__float_as_uint(p1) + 0x8000u) >> 16);
            }
        }
        bf16x8 ap00 = *(const bf16x8*)&QP[(w * 32 + lm) * 64 + fr0];
        bf16x8 ap01 = *(const bf16x8*)&QP[(w * 32 + lm) * 64 + fr1];
        bf16x8 ap10 = *(const bf16x8*)&QP[(w * 32 + 16 + lm) * 64 + fr0];
        bf16x8 ap11 = *(const bf16x8*)&QP[(w * 32 + 16 + lm) * 64 + fr1];
        #pragma unroll
        for (int n = 0; n < 4; ++n) {
            bf16x8 bv0 = *(const bf16x8*)&Vb[cur][(n * 16 + lm) * 64 + fr0];
            bf16x8 bv1 = *(const bf16x8*)&Vb[cur][(n * 16 + lm) * 64 + fr1];
            o0[n] = __builtin_amdgcn_mfma_f32_16x16x32_bf16(ap00, bv0, o0[n], 0, 0, 0);
            o0[n] = __builtin_amdgcn_mfma_f32_16x16x32_bf16(ap01, bv1, o0[n], 0, 0, 0);
            o1[n] = __builtin_amdgcn_mfma_f32_16x16x32_bf16(ap10, bv0, o1[n], 0, 0, 0);
            o1[n] = __builtin_amdgcn_mfma_f32_16x16x32_bf16(ap11, bv1, o1[n], 0, 0, 0);
        }
        lacc0 = __builtin_amdgcn_mfma_f32_16x16x32_bf16(ap00, ones, lacc0, 0, 0, 0);
        lacc0 = __builtin_amdgcn_mfma_f32_16x16x32_bf16(ap01, ones, lacc0, 0, 0, 0);
        lacc1 = __builtin_amdgcn_mfma_f32_16x16x32_bf16(ap10, ones, lacc1, 0, 0, 0);
        lacc1 = __builtin_amdgcn_mfma_f32_16x16x32_bf16(ap11, ones, lacc1, 0, 0, 0);
        __syncthreads();   // all waves done with cur; nxt DMA drained
    }

    #pragma unroll
    for (int e = 0; e < 4; ++e) {
        float inv0 = 1.0f / lacc0[e];
        float inv1 = 1.0f / lacc1[e];
        int row0 = q0 + w * 32 + lq * 4 + e;
        u16* d0 = ctx + (row_b + row0) * D_MODEL + ccol;
        u16* d1 = ctx + (row_b + row0 + 16) * D_MODEL + ccol;
        #pragma unroll
        for (int n = 0; n < 4; ++n) {
            d0[n * 16 + lm] = f2bf(o0[n][e] * inv0);
            d1[n * 16 + lm] = f2bf(o1[n][e] * inv1);
        }
    }
}

// ---------------------------------------------------------------------------
// out = LayerNorm(bf16 C0 + bf16 C1 + cbias + resid) * g + beta.
// ---------------------------------------------------------------------------
template<int OUTF32, int RESBF>
__global__ __launch_bounds__(256)
void add_ln(const u16* __restrict__ C0, const u16* __restrict__ C1,
            const float* __restrict__ cbias, const void* __restrict__ resid,
            const float* __restrict__ g, const float* __restrict__ beta,
            float* __restrict__ outf, u16* __restrict__ outb)
{
    __shared__ float red[8];
    const int row = blockIdx.x;
    const int tid = threadIdx.x;
    u16x4 p0 = ((const u16x4*)(C0 + (size_t)row * D_MODEL))[tid];
    u16x4 p1 = ((const u16x4*)(C1 + (size_t)row * D_MODEL))[tid];
    float4 cb = ((const float4*)cbias)[tid];
    float4 rr;
    if (RESBF) {
        u16x4 rb = ((const u16x4*)((const u16*)resid + (size_t)row * D_MODEL))[tid];
        rr = { bf2f(rb.x), bf2f(rb.y), bf2f(rb.z), bf2f(rb.w) };
    } else {
        rr = ((const float4*)((const float*)resid + (size_t)row * D_MODEL))[tid];
    }
    float4 v = { bf2f(p0.x) + bf2f(p1.x) + cb.x + rr.x,
                 bf2f(p0.y) + bf2f(p1.y) + cb.y + rr.y,
                 bf2f(p0.z) + bf2f(p1.z) + cb.z + rr.z,
                 bf2f(p0.w) + bf2f(p1.w) + cb.w + rr.w };
    float s  = v.x + v.y + v.z + v.w;
    float sq = v.x*v.x + v.y*v.y + v.z*v.z + v.w*v.w;
    #pragma unroll
    for (int off = 32; off > 0; off >>= 1) {
        s  += __shfl_down(s,  off, 64);
        sq += __shfl_down(sq, off, 64);
    }
    const int wv = tid >> 6;
    if ((tid & 63) == 0) { red[wv] = s; red[4 + wv] = sq; }
    __syncthreads();
    float st  = red[0] + red[1] + red[2] + red[3];
    float sqt = red[4] + red[5] + red[6] + red[7];
    float mu   = st * (1.0f / D_MODEL);
    float var  = sqt * (1.0f / D_MODEL) - mu * mu;
    float rstd = rsqrtf(var + EPSLN);
    float4 gv = ((const float4*)g)[tid];
    float4 bt = ((const float4*)beta)[tid];
    float4 ov;
    ov.x = (v.x - mu) * rstd * gv.x + bt.x;
    ov.y = (v.y - mu) * rstd * gv.y + bt.y;
    ov.z = (v.z - mu) * rstd * gv.z + bt.z;
    ov.w = (v.w - mu) * rstd * gv.w + bt.w;
    if (OUTF32) {
        ((float4*)(outf + (size_t)row * D_MODEL))[tid] = ov;
    } else {
        u16x4 ob = { f2bf(ov.x), f2bf(ov.y), f2bf(ov.z), f2bf(ov.w) };
        ((u16x4*)(outb + (size_t)row * D_MODEL))[tid] = ob;
    }
}

// ---------------------------------------------------------------------------
extern "C" void kernel_launch(void* const* d_in, const int* in_sizes, int n_in,
                              void* d_out, int out_size, void* d_ws, size_t ws_size,
                              hipStream_t stream) {
    const float* x     = (const float*)d_in[0];
    const float* wq    = (const float*)d_in[1];
    const float* bq    = (const float*)d_in[2];
    const float* wk    = (const float*)d_in[3];
    const float* bk    = (const float*)d_in[4];
    const float* wv    = (const float*)d_in[5];
    const float* bv    = (const float*)d_in[6];
    const float* wo    = (const float*)d_in[7];
    const float* bo    = (const float*)d_in[8];
    const float* g1    = (const float*)d_in[9];
    const float* b1    = (const float*)d_in[10];
    const float* w_ff1 = (const float*)d_in[11];
    const float* b_ff1 = (const float*)d_in[12];
    const float* w_ff2 = (const float*)d_in[13];
    const float* b_ff2 = (const float*)d_in[14];
    const float* g2    = (const float*)d_in[15];
    const float* b2    = (const float*)d_in[16];
    float* out = (float*)d_out;

    const float qscale = 0.18033688011112042f;   // log2(e) / sqrt(DK)

    char* W = (char*)d_ws;
    u16*   x_bf    = (u16*)(W + 0);             // 8.4 MB (later: ctx)
    u16*   wqkvT   = (u16*)(W + 8388608);       // 6.3 MB
    u16*   woT     = (u16*)(W + 14680064);      // 2.1 MB
    u16*   wff1T   = (u16*)(W + 16777216);      // 8.4 MB
    u16*   wff2T   = (u16*)(W + 25165824);      // 8.4 MB
    u16*   QKV     = (u16*)(W + 33554432);      // 25.2 MB (later: ff1)
    u16*   VtG     = (u16*)(W + 58720256);      // 8.4 MB
    u16*   C0      = (u16*)(W + 67108864);      // 8.4 MB (split-K partial 0)
    u16*   C1      = (u16*)(W + 75497472);      // 8.4 MB (split-K partial 1)
    u16*   h_bf    = (u16*)(W + 83886080);      // 8.4 MB
    float* qkv_bias= (float*)(W + 92274688);    // 12 KB
    u16*   ctx     = x_bf;
    u16*   ff1_bf  = QKV;

    dim3 blk(256);
    prep<<<7180, blk, 0, stream>>>(x, x_bf, wq, wk, wv, wo, w_ff1, w_ff2,
                                   wqkvT, woT, wff1T, wff2T,
                                   bq, bk, bv, qkv_bias, qscale);
    gemm_bf16<4><<<dim3(24, 32, 1), blk, 0, stream>>>(x_bf, wqkvT, qkv_bias, QKV, VtG, MTOT, 3072, 1024, 1024);
    attn_mfma<<<dim3(16, 32), blk, 0, stream>>>(QKV, VtG, ctx);
    gemm_bf16<3><<<dim3(8, 32, 2), blk, 0, stream>>>(ctx, woT, nullptr, C0, nullptr, MTOT, 1024, 512, 1024);
    add_ln<0, 0><<<MTOT, blk, 0, stream>>>(C0, C1, bo, x, g1, b1, nullptr, h_bf);
    gemm_bf16<1><<<dim3(32, 32, 1), blk, 0, stream>>>(h_bf, wff1T, b_ff1, ff1_bf, nullptr, MTOT, DFF_, 1024, 1024);
    gemm_bf16<3><<<dim3(8, 32, 2), blk, 0, stream>>>(ff1_bf, wff2T, nullptr, C0, nullptr, MTOT, 1024, 2048, 4096);
    add_ln<1, 1><<<MTOT, blk, 0, stream>>>(C0, C1, b_ff2, h_bf, g2, b2, out, nullptr);
}